// Round 1
// baseline (562.027 us; speedup 1.0000x reference)
//
#include <hip/hip_runtime.h>
#include <stdint.h>

typedef __attribute__((ext_vector_type(8))) __bf16 bf16x8;
typedef __attribute__((ext_vector_type(4))) float f32x4;
typedef unsigned short u16;

#define LOG2E 1.44269504088896f

static_assert(sizeof(bf16x8) == 16, "bf16x8 must be 16B");

__device__ __forceinline__ u16 f2bf(float f) {
  unsigned u = __builtin_bit_cast(unsigned, f);
  u += 0x7fffu + ((u >> 16) & 1u);   // round-to-nearest-even
  return (u16)(u >> 16);
}

__device__ __forceinline__ void load_lds16(const void* g, void* l) {
  __builtin_amdgcn_global_load_lds((const __attribute__((address_space(1))) void*)g,
                                   (__attribute__((address_space(3))) void*)l, 16, 0, 0);
}

// ---------------- prep: tmp = W @ A  ([1280,1280]@[1280,4]) ----------------
__global__ __launch_bounds__(256) void lora_tmp_k(
    const float* __restrict__ wk, const float* __restrict__ wv,
    const float* __restrict__ ka, const float* __restrict__ va,
    float* __restrict__ tk, float* __restrict__ tv) {
  const int i = blockIdx.x;
  const float* W = blockIdx.y ? wv : wk;
  const float* A = blockIdx.y ? va : ka;
  float* T = blockIdx.y ? tv : tk;
  float s0 = 0.f, s1 = 0.f, s2 = 0.f, s3 = 0.f;
  for (int j = threadIdx.x; j < 1280; j += 256) {
    float w = W[(size_t)i * 1280 + j];
    float4 a4 = *(const float4*)(A + (size_t)j * 4);
    s0 += w * a4.x; s1 += w * a4.y; s2 += w * a4.z; s3 += w * a4.w;
  }
#pragma unroll
  for (int m = 1; m < 64; m <<= 1) {
    s0 += __shfl_xor(s0, m); s1 += __shfl_xor(s1, m);
    s2 += __shfl_xor(s2, m); s3 += __shfl_xor(s3, m);
  }
  __shared__ float red[4][4];
  const int wv_ = threadIdx.x >> 6;
  if ((threadIdx.x & 63) == 0) {
    red[wv_][0] = s0; red[wv_][1] = s1; red[wv_][2] = s2; red[wv_][3] = s3;
  }
  __syncthreads();
  if (threadIdx.x < 4) {
    float r = red[0][threadIdx.x] + red[1][threadIdx.x] + red[2][threadIdx.x] + red[3][threadIdx.x];
    T[(size_t)i * 4 + threadIdx.x] = r;
  }
}

// ------- prep: WT[o][i] = bf16( W[i][o] + sum_r tmp[i][r]*LB[r][o] ) -------
__global__ void wt_prep_k(const float* __restrict__ W, const float* __restrict__ tmp,
                          const float* __restrict__ LB, u16* __restrict__ WT) {
  __shared__ float tile[32][33];
  const int o0 = blockIdx.x * 32, i0 = blockIdx.y * 32;
  const int tx = threadIdx.x, ty = threadIdx.y;
#pragma unroll
  for (int kk = 0; kk < 4; ++kk) {
    int i = i0 + ty + kk * 8, o = o0 + tx;
    float v = W[(size_t)i * 1280 + o];
    if (tmp) {
      float4 t = *(const float4*)(tmp + (size_t)i * 4);
      v += t.x * LB[o] + t.y * LB[1280 + o] + t.z * LB[2560 + o] + t.w * LB[3840 + o];
    }
    tile[ty + kk * 8][tx] = v;
  }
  __syncthreads();
#pragma unroll
  for (int kk = 0; kk < 4; ++kk) {
    int o = o0 + ty + kk * 8, i = i0 + tx;
    WT[(size_t)o * 1280 + i] = f2bf(tile[tx][ty + kk * 8]);
  }
}

// ---------------- fp32 -> bf16 convert (float4 vectorized) ----------------
__global__ __launch_bounds__(256) void cvt_bf16_k(const float* __restrict__ in,
                                                  u16* __restrict__ out, int n4) {
  for (int i = blockIdx.x * 256 + threadIdx.x; i < n4; i += gridDim.x * 256) {
    float4 v = ((const float4*)in)[i];
    ushort4 o;
    o.x = f2bf(v.x); o.y = f2bf(v.y); o.z = f2bf(v.z); o.w = f2bf(v.w);
    ((ushort4*)out)[i] = o;
  }
}

// --------- V [B*S,1280] -> VT [B*1280, 4096] (bf16 tiled transpose) --------
__global__ void vtrans_k(const u16* __restrict__ V, u16* __restrict__ VT) {
  __shared__ u16 tile[32][33];
  const int s0 = blockIdx.x * 32, c0 = blockIdx.y * 32, b = blockIdx.z;
  const int tx = threadIdx.x, ty = threadIdx.y;
#pragma unroll
  for (int kk = 0; kk < 4; ++kk)
    tile[ty + kk * 8][tx] = V[(size_t)(b * 4096 + s0 + ty + kk * 8) * 1280 + c0 + tx];
  __syncthreads();
#pragma unroll
  for (int kk = 0; kk < 4; ++kk)
    VT[(size_t)(b * 1280 + c0 + ty + kk * 8) * 4096 + s0 + tx] = tile[tx][ty + kk * 8];
}

// ------------------- 128x128-tile bf16 MFMA GEMM (BK=32) -------------------
// A: [M,1280] bf16 row-major.  WT: [1280,1280] bf16, [out,in] layout.
// LDS rows padded to 40 elems (80 B) => 2-way bank aliasing (free), and
// 80 B = 5 x 16 B so global_load_lds lane placement never straddles rows.
template <bool F32OUT>
__global__ __launch_bounds__(256) void gemm128_k(
    const u16* __restrict__ A, const u16* __restrict__ WT,
    void* __restrict__ outp, const float* __restrict__ bias, float oscale) {
  __shared__ __align__(16) u16 lds[2 * 128 * 40];
  u16* ldsA = lds;
  u16* ldsB = lds + 128 * 40;
  const int tid = threadIdx.x;
  const int lane = tid & 63, lrow = lane & 15, lhi = lane >> 4;
  const int w = tid >> 6, wm = w >> 1, wn = w & 1;
  const size_t M0 = (size_t)blockIdx.x * 128, N0 = (size_t)blockIdx.y * 128;
  const int wb = tid & 192;
  f32x4 acc[4][4] = {};

  for (int k0 = 0; k0 < 1280; k0 += 32) {
#pragma unroll
    for (int j = 0; j < 3; ++j) {
      if (j < 2 || tid < 128) {
        int i = j * 256 + tid;
        int row = i / 5, c = i % 5; c = c < 4 ? c : 3;
        load_lds16(A + (M0 + row) * 1280 + k0 + c * 8, ldsA + (j * 256 + wb) * 8);
      }
    }
#pragma unroll
    for (int j = 0; j < 3; ++j) {
      if (j < 2 || tid < 128) {
        int i = j * 256 + tid;
        int row = i / 5, c = i % 5; c = c < 4 ? c : 3;
        load_lds16(WT + (N0 + row) * 1280 + k0 + c * 8, ldsB + (j * 256 + wb) * 8);
      }
    }
    __syncthreads();
    bf16x8 af[4], bfr[4];
#pragma unroll
    for (int m = 0; m < 4; ++m)
      af[m] = *(const bf16x8*)(ldsA + (wm * 64 + m * 16 + lrow) * 40 + lhi * 8);
#pragma unroll
    for (int n = 0; n < 4; ++n)
      bfr[n] = *(const bf16x8*)(ldsB + (wn * 64 + n * 16 + lrow) * 40 + lhi * 8);
#pragma unroll
    for (int m = 0; m < 4; ++m)
#pragma unroll
      for (int n = 0; n < 4; ++n)
        acc[m][n] = __builtin_amdgcn_mfma_f32_16x16x32_bf16(af[m], bfr[n], acc[m][n], 0, 0, 0);
    __syncthreads();
  }

#pragma unroll
  for (int m = 0; m < 4; ++m)
#pragma unroll
    for (int n = 0; n < 4; ++n)
#pragma unroll
      for (int r = 0; r < 4; ++r) {
        size_t row = M0 + wm * 64 + m * 16 + lhi * 4 + r;
        size_t col = N0 + wn * 64 + n * 16 + lrow;
        float v = acc[m][n][r];
        if (F32OUT)
          ((float*)outp)[row * 1280 + col] = v + bias[col];
        else
          ((u16*)outp)[row * 1280 + col] = f2bf(v * oscale);
      }
}

// --------------------------- flash attention -------------------------------
// grid (16 bh, 64 qtiles), 256 thr = 4 waves x 16 q-rows. QBLK=KVBLK=64.
// K_lds rows padded to 168 elems (336 B = 21x16B), VT/P rows to 72 (144 B = 9x16B):
// all <=2-way bank conflicts, all global_load_lds-compatible (no row straddle).
__global__ __launch_bounds__(256) void attn_k(
    const u16* __restrict__ Q, const u16* __restrict__ K,
    const u16* __restrict__ VT, u16* __restrict__ AO) {
  __shared__ __align__(16) u16 K_lds[64 * 168];
  __shared__ __align__(16) u16 VT_lds[160 * 72];
  __shared__ __align__(16) u16 P_lds[64 * 72];
  const int tid = threadIdx.x;
  const int lane = tid & 63, lrow = lane & 15, lhi = lane >> 4;
  const int w = tid >> 6;
  const int bh = blockIdx.x, qt = blockIdx.y;
  const int b = bh >> 3, h = bh & 7;
  const int wb = tid & 192;

  // stage Q (reuses K_lds), preload per-wave Q fragments into registers
#pragma unroll
  for (int j = 0; j < 6; ++j) {
    int i = j * 256 + tid;
    if (i < 1344) {
      int row = i / 21, c = i % 21; c = c < 20 ? c : 19;
      load_lds16(Q + (size_t)(b * 4096 + qt * 64 + row) * 1280 + h * 160 + c * 8,
                 K_lds + (j * 256 + wb) * 8);
    }
  }
  __syncthreads();
  bf16x8 qf[5];
#pragma unroll
  for (int kk = 0; kk < 5; ++kk)
    qf[kk] = *(const bf16x8*)(K_lds + (w * 16 + lrow) * 168 + kk * 32 + lhi * 8);
  __syncthreads();

  float m_run[4] = {-1e30f, -1e30f, -1e30f, -1e30f};
  float l_run[4] = {0.f, 0.f, 0.f, 0.f};
  f32x4 o_acc[10] = {};

  for (int kv0 = 0; kv0 < 4096; kv0 += 64) {
    // stage K tile [64][160] (padded rows)
#pragma unroll
    for (int j = 0; j < 6; ++j) {
      int i = j * 256 + tid;
      if (i < 1344) {
        int row = i / 21, c = i % 21; c = c < 20 ? c : 19;
        load_lds16(K + (size_t)(b * 4096 + kv0 + row) * 1280 + h * 160 + c * 8,
                   K_lds + (j * 256 + wb) * 8);
      }
    }
    // stage VT tile [160][64] (padded rows)
#pragma unroll
    for (int j = 0; j < 6; ++j) {
      int i = j * 256 + tid;
      if (i < 1440) {
        int row = i / 9, c = i % 9; c = c < 8 ? c : 7;
        load_lds16(VT + (size_t)(b * 1280 + h * 160 + row) * 4096 + kv0 + c * 8,
                   VT_lds + (j * 256 + wb) * 8);
      }
    }
    __syncthreads();

    // S = Q K^T  (Q pre-scaled by 1/sqrt(dh) in projection epilogue)
    f32x4 sacc[4] = {};
#pragma unroll
    for (int kk = 0; kk < 5; ++kk)
#pragma unroll
      for (int n = 0; n < 4; ++n) {
        bf16x8 kf = *(const bf16x8*)(K_lds + (n * 16 + lrow) * 168 + kk * 32 + lhi * 8);
        sacc[n] = __builtin_amdgcn_mfma_f32_16x16x32_bf16(qf[kk], kf, sacc[n], 0, 0, 0);
      }

    // online softmax (rows = lhi*4+r within this wave's 16 rows)
    float rmax[4], mnew[4], alpha[4], rsum[4];
#pragma unroll
    for (int r = 0; r < 4; ++r)
      rmax[r] = fmaxf(fmaxf(sacc[0][r], sacc[1][r]), fmaxf(sacc[2][r], sacc[3][r]));
#pragma unroll
    for (int m = 1; m < 16; m <<= 1)
#pragma unroll
      for (int r = 0; r < 4; ++r)
        rmax[r] = fmaxf(rmax[r], __shfl_xor(rmax[r], m));
#pragma unroll
    for (int r = 0; r < 4; ++r) {
      mnew[r] = fmaxf(m_run[r], rmax[r]);
      alpha[r] = __builtin_amdgcn_exp2f((m_run[r] - mnew[r]) * LOG2E);
      rsum[r] = 0.f;
    }
    u16 pb[4][4];
#pragma unroll
    for (int n = 0; n < 4; ++n)
#pragma unroll
      for (int r = 0; r < 4; ++r) {
        float p = __builtin_amdgcn_exp2f((sacc[n][r] - mnew[r]) * LOG2E);
        rsum[r] += p;
        pb[n][r] = f2bf(p);
      }
#pragma unroll
    for (int m = 1; m < 16; m <<= 1)
#pragma unroll
      for (int r = 0; r < 4; ++r)
        rsum[r] += __shfl_xor(rsum[r], m);
    f32x4 av;
#pragma unroll
    for (int r = 0; r < 4; ++r) {
      l_run[r] = l_run[r] * alpha[r] + rsum[r];
      m_run[r] = mnew[r];
      av[r] = alpha[r];
    }
#pragma unroll
    for (int c = 0; c < 10; ++c) o_acc[c] *= av;

    // P -> LDS (wave-local rows; no cross-wave barrier needed)
#pragma unroll
    for (int n = 0; n < 4; ++n)
#pragma unroll
      for (int r = 0; r < 4; ++r)
        P_lds[(w * 16 + lhi * 4 + r) * 72 + n * 16 + lrow] = pb[n][r];

    bf16x8 pa[2];
#pragma unroll
    for (int ks = 0; ks < 2; ++ks)
      pa[ks] = *(const bf16x8*)(P_lds + (w * 16 + lrow) * 72 + ks * 32 + lhi * 8);
#pragma unroll
    for (int c = 0; c < 10; ++c)
#pragma unroll
      for (int ks = 0; ks < 2; ++ks) {
        bf16x8 vf = *(const bf16x8*)(VT_lds + (c * 16 + lrow) * 72 + ks * 32 + lhi * 8);
        o_acc[c] = __builtin_amdgcn_mfma_f32_16x16x32_bf16(pa[ks], vf, o_acc[c], 0, 0, 0);
      }
    __syncthreads();
  }

  float invl[4];
#pragma unroll
  for (int r = 0; r < 4; ++r) invl[r] = 1.f / l_run[r];
#pragma unroll
  for (int c = 0; c < 10; ++c)
#pragma unroll
    for (int r = 0; r < 4; ++r)
      AO[(size_t)(b * 4096 + qt * 64 + w * 16 + lhi * 4 + r) * 1280 + h * 160 + c * 16 + lrow]
          = f2bf(o_acc[c][r] * invl[r]);
}

// ---------------------------------------------------------------------------
extern "C" void kernel_launch(void* const* d_in, const int* in_sizes, int n_in,
                              void* d_out, int out_size, void* d_ws, size_t ws_size,
                              hipStream_t stream) {
  const float* hs  = (const float*)d_in[0];
  const float* w_q = (const float*)d_in[1];
  const float* w_k = (const float*)d_in[2];
  const float* w_v = (const float*)d_in[3];
  const float* lka = (const float*)d_in[4];
  const float* lkb = (const float*)d_in[5];
  const float* lva = (const float*)d_in[6];
  const float* lvb = (const float*)d_in[7];
  const float* w_o = (const float*)d_in[8];
  const float* b_o = (const float*)d_in[9];
  float* out = (float*)d_out;
  char* ws = (char*)d_ws;

  const size_t KA  = 0;                      // 1280*4 f32
  const size_t VA  = 20480;
  const size_t WTQ = 40960;                  // 1280*1280 bf16 each
  const size_t WTK = WTQ + 3276800;
  const size_t WTV = WTK + 3276800;
  const size_t WTO = WTV + 3276800;
  const size_t HSB = WTO + 3276800;          // 8192*1280 bf16 each below
  const size_t QB  = HSB + 20971520;
  const size_t KB  = QB + 20971520;
  const size_t VB  = KB + 20971520;
  const size_t VTB = VB + 20971520;
  const size_t AOB = VTB + 20971520;
  const size_t END = AOB + 20971520;
  if (ws_size < END) return;  // leaves poison -> clear validation failure

  float* tk = (float*)(ws + KA);
  float* tv = (float*)(ws + VA);
  u16* wtq = (u16*)(ws + WTQ);
  u16* wtk = (u16*)(ws + WTK);
  u16* wtv = (u16*)(ws + WTV);
  u16* wto = (u16*)(ws + WTO);
  u16* hsb = (u16*)(ws + HSB);
  u16* qb  = (u16*)(ws + QB);
  u16* kb  = (u16*)(ws + KB);
  u16* vb  = (u16*)(ws + VB);
  u16* vtb = (u16*)(ws + VTB);
  u16* aob = (u16*)(ws + AOB);

  lora_tmp_k<<<dim3(1280, 2), 256, 0, stream>>>(w_k, w_v, lka, lva, tk, tv);
  wt_prep_k<<<dim3(40, 40), dim3(32, 8), 0, stream>>>(w_q, nullptr, nullptr, wtq);
  wt_prep_k<<<dim3(40, 40), dim3(32, 8), 0, stream>>>(w_k, tk, lkb, wtk);
  wt_prep_k<<<dim3(40, 40), dim3(32, 8), 0, stream>>>(w_v, tv, lvb, wtv);
  wt_prep_k<<<dim3(40, 40), dim3(32, 8), 0, stream>>>(w_o, nullptr, nullptr, wto);
  cvt_bf16_k<<<2048, 256, 0, stream>>>(hs, hsb, 2621440);

  const float qscale = 0.07905694150420949f;  // 1/sqrt(160)
  gemm128_k<false><<<dim3(64, 10), 256, 0, stream>>>(hsb, wtq, qb, nullptr, qscale);
  gemm128_k<false><<<dim3(64, 10), 256, 0, stream>>>(hsb, wtk, kb, nullptr, 1.0f);
  gemm128_k<false><<<dim3(64, 10), 256, 0, stream>>>(hsb, wtv, vb, nullptr, 1.0f);
  vtrans_k<<<dim3(128, 40, 2), dim3(32, 8), 0, stream>>>(vb, vtb);
  attn_k<<<dim3(16, 64), 256, 0, stream>>>(qb, kb, vtb, aob);
  gemm128_k<true><<<dim3(64, 10), 256, 0, stream>>>(aob, wto, (void*)out, b_o, 1.0f);
}

// Round 2
// 463.526 us; speedup vs baseline: 1.2125x; 1.2125x over previous
//
#include <hip/hip_runtime.h>
#include <stdint.h>

typedef __attribute__((ext_vector_type(8))) __bf16 bf16x8;
typedef __attribute__((ext_vector_type(4))) float f32x4;
typedef unsigned short u16;

#define LOG2E 1.44269504088896f

static_assert(sizeof(bf16x8) == 16, "bf16x8 must be 16B");

__device__ __forceinline__ u16 f2bf(float f) {
  unsigned u = __builtin_bit_cast(unsigned, f);
  u += 0x7fffu + ((u >> 16) & 1u);   // round-to-nearest-even
  return (u16)(u >> 16);
}

__device__ __forceinline__ void load_lds16(const void* g, void* l) {
  __builtin_amdgcn_global_load_lds((const __attribute__((address_space(1))) void*)g,
                                   (__attribute__((address_space(3))) void*)l, 16, 0, 0);
}

// ---------------- prep: tmp = W @ A  ([1280,1280]@[1280,4]) ----------------
__global__ __launch_bounds__(256) void lora_tmp_k(
    const float* __restrict__ wk, const float* __restrict__ wv,
    const float* __restrict__ ka, const float* __restrict__ va,
    float* __restrict__ tk, float* __restrict__ tv) {
  const int i = blockIdx.x;
  const float* W = blockIdx.y ? wv : wk;
  const float* A = blockIdx.y ? va : ka;
  float* T = blockIdx.y ? tv : tk;
  float s0 = 0.f, s1 = 0.f, s2 = 0.f, s3 = 0.f;
  for (int j = threadIdx.x; j < 1280; j += 256) {
    float w = W[(size_t)i * 1280 + j];
    float4 a4 = *(const float4*)(A + (size_t)j * 4);
    s0 += w * a4.x; s1 += w * a4.y; s2 += w * a4.z; s3 += w * a4.w;
  }
#pragma unroll
  for (int m = 1; m < 64; m <<= 1) {
    s0 += __shfl_xor(s0, m); s1 += __shfl_xor(s1, m);
    s2 += __shfl_xor(s2, m); s3 += __shfl_xor(s3, m);
  }
  __shared__ float red[4][4];
  const int wv_ = threadIdx.x >> 6;
  if ((threadIdx.x & 63) == 0) {
    red[wv_][0] = s0; red[wv_][1] = s1; red[wv_][2] = s2; red[wv_][3] = s3;
  }
  __syncthreads();
  if (threadIdx.x < 4) {
    float r = red[0][threadIdx.x] + red[1][threadIdx.x] + red[2][threadIdx.x] + red[3][threadIdx.x];
    T[(size_t)i * 4 + threadIdx.x] = r;
  }
}

// ------- prep: WT[o][i] = bf16( W[i][o] + sum_r tmp[i][r]*LB[r][o] ) -------
__global__ void wt_prep_k(const float* __restrict__ W, const float* __restrict__ tmp,
                          const float* __restrict__ LB, u16* __restrict__ WT) {
  __shared__ float tile[32][33];
  const int o0 = blockIdx.x * 32, i0 = blockIdx.y * 32;
  const int tx = threadIdx.x, ty = threadIdx.y;
#pragma unroll
  for (int kk = 0; kk < 4; ++kk) {
    int i = i0 + ty + kk * 8, o = o0 + tx;
    float v = W[(size_t)i * 1280 + o];
    if (tmp) {
      float4 t = *(const float4*)(tmp + (size_t)i * 4);
      v += t.x * LB[o] + t.y * LB[1280 + o] + t.z * LB[2560 + o] + t.w * LB[3840 + o];
    }
    tile[ty + kk * 8][tx] = v;
  }
  __syncthreads();
#pragma unroll
  for (int kk = 0; kk < 4; ++kk) {
    int o = o0 + ty + kk * 8, i = i0 + tx;
    WT[(size_t)o * 1280 + i] = f2bf(tile[tx][ty + kk * 8]);
  }
}

// ---------------- fp32 -> bf16 convert (float4 vectorized) ----------------
__global__ __launch_bounds__(256) void cvt_bf16_k(const float* __restrict__ in,
                                                  u16* __restrict__ out, int n4) {
  for (int i = blockIdx.x * 256 + threadIdx.x; i < n4; i += gridDim.x * 256) {
    float4 v = ((const float4*)in)[i];
    ushort4 o;
    o.x = f2bf(v.x); o.y = f2bf(v.y); o.z = f2bf(v.z); o.w = f2bf(v.w);
    ((ushort4*)out)[i] = o;
  }
}

// --------- V [B*S,1280] -> VT [B*1280, 4096] (bf16 tiled transpose) --------
__global__ void vtrans_k(const u16* __restrict__ V, u16* __restrict__ VT) {
  __shared__ u16 tile[32][33];
  const int s0 = blockIdx.x * 32, c0 = blockIdx.y * 32, b = blockIdx.z;
  const int tx = threadIdx.x, ty = threadIdx.y;
#pragma unroll
  for (int kk = 0; kk < 4; ++kk)
    tile[ty + kk * 8][tx] = V[(size_t)(b * 4096 + s0 + ty + kk * 8) * 1280 + c0 + tx];
  __syncthreads();
#pragma unroll
  for (int kk = 0; kk < 4; ++kk)
    VT[(size_t)(b * 1280 + c0 + ty + kk * 8) * 4096 + s0 + tx] = tile[tx][ty + kk * 8];
}

// ------------------- 128x128-tile bf16 MFMA GEMM (BK=32) -------------------
template <bool F32OUT>
__global__ __launch_bounds__(256) void gemm128_k(
    const u16* __restrict__ A, const u16* __restrict__ WT,
    void* __restrict__ outp, const float* __restrict__ bias, float oscale) {
  __shared__ __align__(16) u16 lds[2 * 128 * 40];
  u16* ldsA = lds;
  u16* ldsB = lds + 128 * 40;
  const int tid = threadIdx.x;
  const int lane = tid & 63, lrow = lane & 15, lhi = lane >> 4;
  const int w = tid >> 6, wm = w >> 1, wn = w & 1;
  const size_t M0 = (size_t)blockIdx.x * 128, N0 = (size_t)blockIdx.y * 128;
  const int wb = tid & 192;
  f32x4 acc[4][4] = {};

  for (int k0 = 0; k0 < 1280; k0 += 32) {
#pragma unroll
    for (int j = 0; j < 3; ++j) {
      if (j < 2 || tid < 128) {
        int i = j * 256 + tid;
        int row = i / 5, c = i % 5; c = c < 4 ? c : 3;
        load_lds16(A + (M0 + row) * 1280 + k0 + c * 8, ldsA + (j * 256 + wb) * 8);
      }
    }
#pragma unroll
    for (int j = 0; j < 3; ++j) {
      if (j < 2 || tid < 128) {
        int i = j * 256 + tid;
        int row = i / 5, c = i % 5; c = c < 4 ? c : 3;
        load_lds16(WT + (N0 + row) * 1280 + k0 + c * 8, ldsB + (j * 256 + wb) * 8);
      }
    }
    __syncthreads();
    bf16x8 af[4], bfr[4];
#pragma unroll
    for (int m = 0; m < 4; ++m)
      af[m] = *(const bf16x8*)(ldsA + (wm * 64 + m * 16 + lrow) * 40 + lhi * 8);
#pragma unroll
    for (int n = 0; n < 4; ++n)
      bfr[n] = *(const bf16x8*)(ldsB + (wn * 64 + n * 16 + lrow) * 40 + lhi * 8);
#pragma unroll
    for (int m = 0; m < 4; ++m)
#pragma unroll
      for (int n = 0; n < 4; ++n)
        acc[m][n] = __builtin_amdgcn_mfma_f32_16x16x32_bf16(af[m], bfr[n], acc[m][n], 0, 0, 0);
    __syncthreads();
  }

#pragma unroll
  for (int m = 0; m < 4; ++m)
#pragma unroll
    for (int n = 0; n < 4; ++n)
#pragma unroll
      for (int r = 0; r < 4; ++r) {
        size_t row = M0 + wm * 64 + m * 16 + lhi * 4 + r;
        size_t col = N0 + wn * 64 + n * 16 + lrow;
        float v = acc[m][n][r];
        if (F32OUT)
          ((float*)outp)[row * 1280 + col] = v + bias[col];
        else
          ((u16*)outp)[row * 1280 + col] = f2bf(v * oscale);
      }
}

// --------------------------- flash attention -------------------------------
// grid (16 bh, 32 qtiles), 256 thr = 4 waves x 32 q-rows each. QBLK=128, KVBLK=64.
// Each wave owns M=32 rows (2 m-frags) so every K/VT fragment read from LDS
// feeds 2 MFMAs (FLOP/LDS-byte doubled vs R1). Q lives in registers.
// K_lds rows padded to 168 elems (336 B), VT/P rows to 72 (144 B): <=2-way
// bank conflicts, global_load_lds-compatible (rows = whole 16B chunks).
__global__ __launch_bounds__(256, 2) void attn_k(
    const u16* __restrict__ Q, const u16* __restrict__ K,
    const u16* __restrict__ VT, u16* __restrict__ AO) {
  __shared__ __align__(16) u16 K_lds[64 * 168];
  __shared__ __align__(16) u16 VT_lds[160 * 72];
  __shared__ __align__(16) u16 P_lds[128 * 72];
  const int tid = threadIdx.x;
  const int lane = tid & 63, lrow = lane & 15, lhi = lane >> 4;
  const int w = tid >> 6;
  const int bh = blockIdx.x, qt = blockIdx.y;
  const int b = bh >> 3, h = bh & 7;
  const int wb = tid & 192;

  // Q -> registers (one-time): A-frag row=lrow, cols kk*32+lhi*8
  bf16x8 qf[2][5];
#pragma unroll
  for (int m = 0; m < 2; ++m)
#pragma unroll
    for (int kk = 0; kk < 5; ++kk)
      qf[m][kk] = *(const bf16x8*)(Q + (size_t)(b * 4096 + qt * 128 + w * 32 + m * 16 + lrow) * 1280
                                     + h * 160 + kk * 32 + lhi * 8);

  float m_run[2][4], l_run[2][4];
#pragma unroll
  for (int m = 0; m < 2; ++m)
#pragma unroll
    for (int r = 0; r < 4; ++r) { m_run[m][r] = -1e30f; l_run[m][r] = 0.f; }
  f32x4 o_acc[2][10] = {};

  for (int kv0 = 0; kv0 < 4096; kv0 += 64) {
    // stage K tile [64][160] (padded rows, 21 chunks of 16B per row)
#pragma unroll
    for (int j = 0; j < 6; ++j) {
      int i = j * 256 + tid;
      if (i < 1344) {
        int row = i / 21, c = i % 21; c = c < 20 ? c : 19;
        load_lds16(K + (size_t)(b * 4096 + kv0 + row) * 1280 + h * 160 + c * 8,
                   K_lds + (j * 256 + wb) * 8);
      }
    }
    // stage VT tile [160][64] (padded rows, 9 chunks per row)
#pragma unroll
    for (int j = 0; j < 6; ++j) {
      int i = j * 256 + tid;
      if (i < 1440) {
        int row = i / 9, c = i % 9; c = c < 8 ? c : 7;
        load_lds16(VT + (size_t)(b * 1280 + h * 160 + row) * 4096 + kv0 + c * 8,
                   VT_lds + (j * 256 + wb) * 8);
      }
    }
    __syncthreads();

    // S = Q K^T  (Q pre-scaled). Each kf read feeds both m-frags.
    f32x4 sacc[2][4] = {};
    __builtin_amdgcn_s_setprio(1);
#pragma unroll
    for (int kk = 0; kk < 5; ++kk)
#pragma unroll
      for (int n = 0; n < 4; ++n) {
        bf16x8 kf = *(const bf16x8*)(K_lds + (n * 16 + lrow) * 168 + kk * 32 + lhi * 8);
        sacc[0][n] = __builtin_amdgcn_mfma_f32_16x16x32_bf16(qf[0][kk], kf, sacc[0][n], 0, 0, 0);
        sacc[1][n] = __builtin_amdgcn_mfma_f32_16x16x32_bf16(qf[1][kk], kf, sacc[1][n], 0, 0, 0);
      }
    __builtin_amdgcn_s_setprio(0);

    // online softmax with deferred rescale (T13, THR=8)
    float rmax[2][4];
#pragma unroll
    for (int m = 0; m < 2; ++m)
#pragma unroll
      for (int r = 0; r < 4; ++r)
        rmax[m][r] = fmaxf(fmaxf(sacc[m][0][r], sacc[m][1][r]),
                           fmaxf(sacc[m][2][r], sacc[m][3][r]));
#pragma unroll
    for (int s = 1; s < 16; s <<= 1)
#pragma unroll
      for (int m = 0; m < 2; ++m)
#pragma unroll
        for (int r = 0; r < 4; ++r)
          rmax[m][r] = fmaxf(rmax[m][r], __shfl_xor(rmax[m][r], s));

    int ok = 1;
#pragma unroll
    for (int m = 0; m < 2; ++m)
#pragma unroll
      for (int r = 0; r < 4; ++r)
        ok &= (rmax[m][r] - m_run[m][r] <= 8.0f) ? 1 : 0;
    if (!__all(ok)) {
#pragma unroll
      for (int m = 0; m < 2; ++m) {
        f32x4 av;
#pragma unroll
        for (int r = 0; r < 4; ++r) {
          float mnew = fmaxf(m_run[m][r], rmax[m][r]);
          float alpha = __builtin_amdgcn_exp2f((m_run[m][r] - mnew) * LOG2E);
          l_run[m][r] *= alpha;
          m_run[m][r] = mnew;
          av[r] = alpha;
        }
#pragma unroll
        for (int c = 0; c < 10; ++c) o_acc[m][c] *= av;
      }
    }

    float rsum[2][4] = {};
    u16 pb[2][4][4];
#pragma unroll
    for (int m = 0; m < 2; ++m)
#pragma unroll
      for (int n = 0; n < 4; ++n)
#pragma unroll
        for (int r = 0; r < 4; ++r) {
          float p = __builtin_amdgcn_exp2f((sacc[m][n][r] - m_run[m][r]) * LOG2E);
          rsum[m][r] += p;
          pb[m][n][r] = f2bf(p);
        }
#pragma unroll
    for (int s = 1; s < 16; s <<= 1)
#pragma unroll
      for (int m = 0; m < 2; ++m)
#pragma unroll
        for (int r = 0; r < 4; ++r)
          rsum[m][r] += __shfl_xor(rsum[m][r], s);
#pragma unroll
    for (int m = 0; m < 2; ++m)
#pragma unroll
      for (int r = 0; r < 4; ++r)
        l_run[m][r] += rsum[m][r];

    // P -> LDS (wave-local rows; no cross-wave barrier needed)
#pragma unroll
    for (int m = 0; m < 2; ++m)
#pragma unroll
      for (int n = 0; n < 4; ++n)
#pragma unroll
        for (int r = 0; r < 4; ++r)
          P_lds[(w * 32 + m * 16 + lhi * 4 + r) * 72 + n * 16 + lrow] = pb[m][n][r];

    bf16x8 pa[2][2];
#pragma unroll
    for (int m = 0; m < 2; ++m)
#pragma unroll
      for (int ks = 0; ks < 2; ++ks)
        pa[m][ks] = *(const bf16x8*)(P_lds + (w * 32 + m * 16 + lrow) * 72 + ks * 32 + lhi * 8);

    __builtin_amdgcn_s_setprio(1);
#pragma unroll
    for (int ks = 0; ks < 2; ++ks)
#pragma unroll
      for (int c = 0; c < 10; ++c) {
        bf16x8 vf = *(const bf16x8*)(VT_lds + (c * 16 + lrow) * 72 + ks * 32 + lhi * 8);
        o_acc[0][c] = __builtin_amdgcn_mfma_f32_16x16x32_bf16(pa[0][ks], vf, o_acc[0][c], 0, 0, 0);
        o_acc[1][c] = __builtin_amdgcn_mfma_f32_16x16x32_bf16(pa[1][ks], vf, o_acc[1][c], 0, 0, 0);
      }
    __builtin_amdgcn_s_setprio(0);
    __syncthreads();
  }

  float invl[2][4];
#pragma unroll
  for (int m = 0; m < 2; ++m)
#pragma unroll
    for (int r = 0; r < 4; ++r) invl[m][r] = 1.f / l_run[m][r];
#pragma unroll
  for (int m = 0; m < 2; ++m)
#pragma unroll
    for (int c = 0; c < 10; ++c)
#pragma unroll
      for (int r = 0; r < 4; ++r)
        AO[(size_t)(b * 4096 + qt * 128 + w * 32 + m * 16 + lhi * 4 + r) * 1280
           + h * 160 + c * 16 + lrow] = f2bf(o_acc[m][c][r] * invl[m][r]);
}

// ---------------------------------------------------------------------------
extern "C" void kernel_launch(void* const* d_in, const int* in_sizes, int n_in,
                              void* d_out, int out_size, void* d_ws, size_t ws_size,
                              hipStream_t stream) {
  const float* hs  = (const float*)d_in[0];
  const float* w_q = (const float*)d_in[1];
  const float* w_k = (const float*)d_in[2];
  const float* w_v = (const float*)d_in[3];
  const float* lka = (const float*)d_in[4];
  const float* lkb = (const float*)d_in[5];
  const float* lva = (const float*)d_in[6];
  const float* lvb = (const float*)d_in[7];
  const float* w_o = (const float*)d_in[8];
  const float* b_o = (const float*)d_in[9];
  float* out = (float*)d_out;
  char* ws = (char*)d_ws;

  const size_t KA  = 0;                      // 1280*4 f32
  const size_t VA  = 20480;
  const size_t WTQ = 40960;                  // 1280*1280 bf16 each
  const size_t WTK = WTQ + 3276800;
  const size_t WTV = WTK + 3276800;
  const size_t WTO = WTV + 3276800;
  const size_t HSB = WTO + 3276800;          // 8192*1280 bf16 each below
  const size_t QB  = HSB + 20971520;
  const size_t KB  = QB + 20971520;
  const size_t VB  = KB + 20971520;
  const size_t VTB = VB + 20971520;
  const size_t AOB = VTB + 20971520;
  const size_t END = AOB + 20971520;
  if (ws_size < END) return;  // leaves poison -> clear validation failure

  float* tk = (float*)(ws + KA);
  float* tv = (float*)(ws + VA);
  u16* wtq = (u16*)(ws + WTQ);
  u16* wtk = (u16*)(ws + WTK);
  u16* wtv = (u16*)(ws + WTV);
  u16* wto = (u16*)(ws + WTO);
  u16* hsb = (u16*)(ws + HSB);
  u16* qb  = (u16*)(ws + QB);
  u16* kb  = (u16*)(ws + KB);
  u16* vb  = (u16*)(ws + VB);
  u16* vtb = (u16*)(ws + VTB);
  u16* aob = (u16*)(ws + AOB);

  lora_tmp_k<<<dim3(1280, 2), 256, 0, stream>>>(w_k, w_v, lka, lva, tk, tv);
  wt_prep_k<<<dim3(40, 40), dim3(32, 8), 0, stream>>>(w_q, nullptr, nullptr, wtq);
  wt_prep_k<<<dim3(40, 40), dim3(32, 8), 0, stream>>>(w_k, tk, lkb, wtk);
  wt_prep_k<<<dim3(40, 40), dim3(32, 8), 0, stream>>>(w_v, tv, lvb, wtv);
  wt_prep_k<<<dim3(40, 40), dim3(32, 8), 0, stream>>>(w_o, nullptr, nullptr, wto);
  cvt_bf16_k<<<2048, 256, 0, stream>>>(hs, hsb, 2621440);

  const float qscale = 0.07905694150420949f;  // 1/sqrt(160)
  gemm128_k<false><<<dim3(64, 10), 256, 0, stream>>>(hsb, wtq, qb, nullptr, qscale);
  gemm128_k<false><<<dim3(64, 10), 256, 0, stream>>>(hsb, wtk, kb, nullptr, 1.0f);
  gemm128_k<false><<<dim3(64, 10), 256, 0, stream>>>(hsb, wtv, vb, nullptr, 1.0f);
  vtrans_k<<<dim3(128, 40, 2), dim3(32, 8), 0, stream>>>(vb, vtb);
  attn_k<<<dim3(16, 32), 256, 0, stream>>>(qb, kb, vtb, aob);
  gemm128_k<true><<<dim3(64, 10), 256, 0, stream>>>(aob, wto, (void*)out, b_o, 1.0f);
}

// Round 4
// 383.751 us; speedup vs baseline: 1.4646x; 1.2079x over previous
//
#include <hip/hip_runtime.h>
#include <stdint.h>

typedef __attribute__((ext_vector_type(8))) __bf16 bf16x8;
typedef __attribute__((ext_vector_type(2))) __bf16 bf16x2;
typedef __attribute__((ext_vector_type(4))) float f32x4;
typedef __attribute__((ext_vector_type(16))) float f32x16;
typedef unsigned short u16;

#define LOG2E 1.44269504088896f

static_assert(sizeof(bf16x8) == 16, "bf16x8 must be 16B");

__device__ __forceinline__ u16 f2bf(float f) {
  unsigned u = __builtin_bit_cast(unsigned, f);
  u += 0x7fffu + ((u >> 16) & 1u);   // round-to-nearest-even
  return (u16)(u >> 16);
}

__device__ __forceinline__ void load_lds16(const void* g, void* l) {
  __builtin_amdgcn_global_load_lds((const __attribute__((address_space(1))) void*)g,
                                   (__attribute__((address_space(3))) void*)l, 16, 0, 0);
}

// ---------------- prep: tmp = W @ A  ([1280,1280]@[1280,4]) ----------------
__global__ __launch_bounds__(256) void lora_tmp_k(
    const float* __restrict__ wk, const float* __restrict__ wv,
    const float* __restrict__ ka, const float* __restrict__ va,
    float* __restrict__ tk, float* __restrict__ tv) {
  const int i = blockIdx.x;
  const float* W = blockIdx.y ? wv : wk;
  const float* A = blockIdx.y ? va : ka;
  float* T = blockIdx.y ? tv : tk;
  float s0 = 0.f, s1 = 0.f, s2 = 0.f, s3 = 0.f;
  for (int j = threadIdx.x; j < 1280; j += 256) {
    float w = W[(size_t)i * 1280 + j];
    float4 a4 = *(const float4*)(A + (size_t)j * 4);
    s0 += w * a4.x; s1 += w * a4.y; s2 += w * a4.z; s3 += w * a4.w;
  }
#pragma unroll
  for (int m = 1; m < 64; m <<= 1) {
    s0 += __shfl_xor(s0, m); s1 += __shfl_xor(s1, m);
    s2 += __shfl_xor(s2, m); s3 += __shfl_xor(s3, m);
  }
  __shared__ float red[4][4];
  const int wv_ = threadIdx.x >> 6;
  if ((threadIdx.x & 63) == 0) {
    red[wv_][0] = s0; red[wv_][1] = s1; red[wv_][2] = s2; red[wv_][3] = s3;
  }
  __syncthreads();
  if (threadIdx.x < 4) {
    float r = red[0][threadIdx.x] + red[1][threadIdx.x] + red[2][threadIdx.x] + red[3][threadIdx.x];
    T[(size_t)i * 4 + threadIdx.x] = r;
  }
}

// ------- prep: WT[o][i] = bf16( W[i][o] + sum_r tmp[i][r]*LB[r][o] ) -------
__global__ void wt_prep_k(const float* __restrict__ W, const float* __restrict__ tmp,
                          const float* __restrict__ LB, u16* __restrict__ WT) {
  __shared__ float tile[32][33];
  const int o0 = blockIdx.x * 32, i0 = blockIdx.y * 32;
  const int tx = threadIdx.x, ty = threadIdx.y;
#pragma unroll
  for (int kk = 0; kk < 4; ++kk) {
    int i = i0 + ty + kk * 8, o = o0 + tx;
    float v = W[(size_t)i * 1280 + o];
    if (tmp) {
      float4 t = *(const float4*)(tmp + (size_t)i * 4);
      v += t.x * LB[o] + t.y * LB[1280 + o] + t.z * LB[2560 + o] + t.w * LB[3840 + o];
    }
    tile[ty + kk * 8][tx] = v;
  }
  __syncthreads();
#pragma unroll
  for (int kk = 0; kk < 4; ++kk) {
    int o = o0 + ty + kk * 8, i = i0 + tx;
    WT[(size_t)o * 1280 + i] = f2bf(tile[tx][ty + kk * 8]);
  }
}

// ---------------- fp32 -> bf16 convert (float4 vectorized) ----------------
__global__ __launch_bounds__(256) void cvt_bf16_k(const float* __restrict__ in,
                                                  u16* __restrict__ out, int n4) {
  for (int i = blockIdx.x * 256 + threadIdx.x; i < n4; i += gridDim.x * 256) {
    float4 v = ((const float4*)in)[i];
    ushort4 o;
    o.x = f2bf(v.x); o.y = f2bf(v.y); o.z = f2bf(v.z); o.w = f2bf(v.w);
    ((ushort4*)out)[i] = o;
  }
}

// --------- V [B*S,1280] -> VT [B*1280, 4096] (bf16 tiled transpose) --------
__global__ void vtrans_k(const u16* __restrict__ V, u16* __restrict__ VT) {
  __shared__ u16 tile[32][33];
  const int s0 = blockIdx.x * 32, c0 = blockIdx.y * 32, b = blockIdx.z;
  const int tx = threadIdx.x, ty = threadIdx.y;
#pragma unroll
  for (int kk = 0; kk < 4; ++kk)
    tile[ty + kk * 8][tx] = V[(size_t)(b * 4096 + s0 + ty + kk * 8) * 1280 + c0 + tx];
  __syncthreads();
#pragma unroll
  for (int kk = 0; kk < 4; ++kk)
    VT[(size_t)(b * 1280 + c0 + ty + kk * 8) * 4096 + s0 + tx] = tile[tx][ty + kk * 8];
}

// ------------------- 128x128-tile bf16 MFMA GEMM (BK=32) -------------------
template <bool F32OUT>
__global__ __launch_bounds__(256) void gemm128_k(
    const u16* __restrict__ A, const u16* __restrict__ WT,
    void* __restrict__ outp, const float* __restrict__ bias, float oscale) {
  __shared__ __align__(16) u16 lds[2 * 128 * 40];
  u16* ldsA = lds;
  u16* ldsB = lds + 128 * 40;
  const int tid = threadIdx.x;
  const int lane = tid & 63, lrow = lane & 15, lhi = lane >> 4;
  const int w = tid >> 6, wm = w >> 1, wn = w & 1;
  const size_t M0 = (size_t)blockIdx.x * 128, N0 = (size_t)blockIdx.y * 128;
  const int wb = tid & 192;
  f32x4 acc[4][4] = {};

  for (int k0 = 0; k0 < 1280; k0 += 32) {
#pragma unroll
    for (int j = 0; j < 3; ++j) {
      if (j < 2 || tid < 128) {
        int i = j * 256 + tid;
        int row = i / 5, c = i % 5; c = c < 4 ? c : 3;
        load_lds16(A + (M0 + row) * 1280 + k0 + c * 8, ldsA + (j * 256 + wb) * 8);
      }
    }
#pragma unroll
    for (int j = 0; j < 3; ++j) {
      if (j < 2 || tid < 128) {
        int i = j * 256 + tid;
        int row = i / 5, c = i % 5; c = c < 4 ? c : 3;
        load_lds16(WT + (N0 + row) * 1280 + k0 + c * 8, ldsB + (j * 256 + wb) * 8);
      }
    }
    __syncthreads();
    bf16x8 af[4], bfr[4];
#pragma unroll
    for (int m = 0; m < 4; ++m)
      af[m] = *(const bf16x8*)(ldsA + (wm * 64 + m * 16 + lrow) * 40 + lhi * 8);
#pragma unroll
    for (int n = 0; n < 4; ++n)
      bfr[n] = *(const bf16x8*)(ldsB + (wn * 64 + n * 16 + lrow) * 40 + lhi * 8);
#pragma unroll
    for (int m = 0; m < 4; ++m)
#pragma unroll
      for (int n = 0; n < 4; ++n)
        acc[m][n] = __builtin_amdgcn_mfma_f32_16x16x32_bf16(af[m], bfr[n], acc[m][n], 0, 0, 0);
    __syncthreads();
  }

#pragma unroll
  for (int m = 0; m < 4; ++m)
#pragma unroll
    for (int n = 0; n < 4; ++n)
#pragma unroll
      for (int r = 0; r < 4; ++r) {
        size_t row = M0 + wm * 64 + m * 16 + lhi * 4 + r;
        size_t col = N0 + wn * 64 + n * 16 + lrow;
        float v = acc[m][n][r];
        if (F32OUT)
          ((float*)outp)[row * 1280 + col] = v + bias[col];
        else
          ((u16*)outp)[row * 1280 + col] = f2bf(v * oscale);
      }
}

// --------------------------- flash attention -------------------------------
// grid (16 bh, 32 qt), 256 thr = 4 waves x 32 q-cols. QBLK=128, KVBLK=64.
// Swapped QK^T (S^T = mfma(K,Q), 32x32x16): lane owns one q column ->
// in-register softmax (in-lane reduce + 1 shfl_xor(32)); P assembled
// in-register into PV's B-operand (no P round-trip through LDS).
// Pipeline: K double-buffered, VT single; counted vmcnt (11/6), raw barriers.
// K rows: 24 16B-chunks, XOR-swizzled (slot = (c&24)|((c^row)&7)) -> staging
// is 6 issues/wave uniform AND reads are bank-uniform. VT rows: 8 chunks,
// slot = c^(row&7), 5 issues/wave uniform, bank-uniform reads.
__global__ __launch_bounds__(256, 2) void attn_k(
    const u16* __restrict__ Q, const u16* __restrict__ K,
    const u16* __restrict__ VT, u16* __restrict__ AO) {
  __shared__ __align__(16) u16 lds_all[34816];  // kb0[12288] kb1[12288] vt[10240]
  u16* const kb0 = lds_all;
  u16* const kb1 = lds_all + 12288;
  u16* const vt = lds_all + 24576;
  const int tid = threadIdx.x;
  const int lane = tid & 63;
  const int l31 = lane & 31, lhi5 = lane >> 5;
  const int lo32 = (lane < 32);
  const int w = tid >> 6;
  const int bh = blockIdx.x, qt = blockIdx.y;
  const int b = bh >> 3, h = bh & 7;
  const int wb = tid & 192;

  const u16* Kg = K + (size_t)b * 4096 * 1280 + h * 160;
  const u16* VTg = VT + ((size_t)b * 1280 + h * 160) * 4096;

  // Q -> registers in B-frag layout: lane l31 = q col, k = lhi5*8 + reg
  bf16x8 qf[10];
  const u16* Qg = Q + (size_t)(b * 4096 + qt * 128 + w * 32 + l31) * 1280 + h * 160 + lhi5 * 8;
#pragma unroll
  for (int kf = 0; kf < 10; ++kf) qf[kf] = *(const bf16x8*)(Qg + kf * 16);
#pragma unroll
  for (int kf = 0; kf < 10; ++kf) asm volatile("" : "+v"(qf[kf]));  // force wait pre-loop

  auto stageK = [&](int kv0, u16* dst) {
#pragma unroll
    for (int j = 0; j < 6; ++j) {
      int i = j * 256 + tid;
      int row = i / 24, cl = i % 24;
      int cg = (cl & 24) | ((cl ^ row) & 7);
      cg = cg < 20 ? cg : 19;
      load_lds16(Kg + (size_t)(kv0 + row) * 1280 + cg * 8, dst + (j * 256 + wb) * 8);
    }
  };
  auto stageV = [&](int kv0) {
#pragma unroll
    for (int j = 0; j < 5; ++j) {
      int i = j * 256 + tid;
      int row = i >> 3, cl = i & 7;
      int cg = cl ^ (row & 7);
      load_lds16(VTg + (size_t)row * 4096 + kv0 + cg * 8, vt + (j * 256 + wb) * 8);
    }
  };

  stageK(0, kb0);  // K[0] in flight: 6 outstanding at loop entry

  f32x16 o[5] = {};
  float m_run = -1e30f, l_run = 0.f;

  for (int t = 0; t < 64; ++t) {
    const u16* kcur = (t & 1) ? kb1 : kb0;
    u16* knext = (t & 1) ? kb0 : kb1;
    // (a) issue VT[t] (5) and K[t+1] (6)
    stageV(t * 64);
    if (t < 63) stageK((t + 1) * 64, knext);
    // (b,c) wait K[t] landed (leave VT[t]+K[t+1] in flight), barrier
    if (t < 63) { asm volatile("s_waitcnt vmcnt(11)" ::: "memory"); }
    else        { asm volatile("s_waitcnt vmcnt(5)" ::: "memory"); }
    __builtin_amdgcn_s_barrier();
    __builtin_amdgcn_sched_barrier(0);

    // (d) S^T = mfma(K, Q): sacc[mt] covers kv rows mt*32.. , q col = l31
    f32x16 sacc[2] = {};
    __builtin_amdgcn_s_setprio(1);
#pragma unroll
    for (int kf = 0; kf < 10; ++kf) {
      const int c = 2 * kf + lhi5;
#pragma unroll
      for (int mt = 0; mt < 2; ++mt) {
        const int row = mt * 32 + l31;
        const int slot = (c & 24) | ((c ^ row) & 7);
        bf16x8 ka = *(const bf16x8*)(kcur + row * 192 + slot * 8);
        sacc[mt] = __builtin_amdgcn_mfma_f32_32x32x16_bf16(ka, qf[kf], sacc[mt], 0, 0, 0);
      }
    }
    __builtin_amdgcn_s_setprio(0);

    // online softmax, fully in-register (lane owns q col; partner lane^32)
    float mx = -1e30f;
#pragma unroll
    for (int mt = 0; mt < 2; ++mt)
#pragma unroll
      for (int i = 0; i < 16; ++i) mx = fmaxf(mx, sacc[mt][i]);
    mx = fmaxf(mx, __shfl_xor(mx, 32));
    if (__any(mx - m_run > 8.0f)) {   // deferred rescale (T13)
      float mnew = fmaxf(m_run, mx);
      float al = __builtin_amdgcn_exp2f((m_run - mnew) * LOG2E);
      l_run *= al; m_run = mnew;
#pragma unroll
      for (int dm = 0; dm < 5; ++dm)
#pragma unroll
        for (int i = 0; i < 16; ++i) o[dm][i] *= al;
    }
    float rs = 0.f;
    unsigned xp[2][8];
#pragma unroll
    for (int mt = 0; mt < 2; ++mt)
#pragma unroll
      for (int r = 0; r < 8; ++r) {
        float p0 = __builtin_amdgcn_exp2f((sacc[mt][2 * r] - m_run) * LOG2E);
        float p1 = __builtin_amdgcn_exp2f((sacc[mt][2 * r + 1] - m_run) * LOG2E);
        rs += p0 + p1;
        bf16x2 pk; pk[0] = (__bf16)p0; pk[1] = (__bf16)p1;
        xp[mt][r] = __builtin_bit_cast(unsigned, pk);
      }
    rs += __shfl_xor(rs, 32);
    l_run += rs;

    // (f,g) VT[t] landed (leave K[t+1] in flight), barrier
    if (t < 63) { asm volatile("s_waitcnt vmcnt(6)" ::: "memory"); }
    else        { asm volatile("s_waitcnt vmcnt(0)" ::: "memory"); }
    __builtin_amdgcn_s_barrier();
    __builtin_amdgcn_sched_barrier(0);

    // (h) O^T += mfma(VT, P^T): B-frags assembled in-register from xp
    __builtin_amdgcn_s_setprio(1);
#pragma unroll
    for (int kf = 0; kf < 4; ++kf) {
      const int mt = kf >> 1, hf = kf & 1;
      unsigned xa = xp[mt][hf * 4 + 0], xb = xp[mt][hf * 4 + 1];
      unsigned xc = xp[mt][hf * 4 + 2], xd = xp[mt][hf * 4 + 3];
      unsigned sa = __shfl_xor((int)xa, 32), sb = __shfl_xor((int)xb, 32);
      unsigned sc = __shfl_xor((int)xc, 32), sd = __shfl_xor((int)xd, 32);
      uint4 pw;
      pw.x = lo32 ? xa : sc;
      pw.y = lo32 ? xb : sd;
      pw.z = lo32 ? sa : xc;
      pw.w = lo32 ? sb : xd;
      bf16x8 pB = __builtin_bit_cast(bf16x8, pw);
      const int c = 2 * kf + lhi5;
#pragma unroll
      for (int dm = 0; dm < 5; ++dm) {
        const int row = dm * 32 + l31;
        bf16x8 va = *(const bf16x8*)(vt + row * 64 + ((c ^ (row & 7)) * 8));
        o[dm] = __builtin_amdgcn_mfma_f32_32x32x16_bf16(va, pB, o[dm], 0, 0, 0);
      }
    }
    __builtin_amdgcn_s_setprio(0);
    // (i) all PV reads done -> next iter may overwrite vt / kb[next]
    __builtin_amdgcn_sched_barrier(0);
    __builtin_amdgcn_s_barrier();
    __builtin_amdgcn_sched_barrier(0);
  }

  // epilogue: per-wave LDS transpose (own slice, no barrier) + coalesced store
  float invl = 1.f / l_run;
  u16* tr = lds_all + w * 5376;  // 32 rows x 168 u16
#pragma unroll
  for (int dm = 0; dm < 5; ++dm)
#pragma unroll
    for (int k = 0; k < 4; ++k) {
      int d = dm * 32 + k * 8 + lhi5 * 4;
      unsigned lo_ = (unsigned)f2bf(o[dm][4 * k + 0] * invl) |
                     ((unsigned)f2bf(o[dm][4 * k + 1] * invl) << 16);
      unsigned hi_ = (unsigned)f2bf(o[dm][4 * k + 2] * invl) |
                     ((unsigned)f2bf(o[dm][4 * k + 3] * invl) << 16);
      uint2 u; u.x = lo_; u.y = hi_;
      *(uint2*)(tr + l31 * 168 + d) = u;
    }
  asm volatile("s_waitcnt lgkmcnt(0)" ::: "memory");
  __builtin_amdgcn_sched_barrier(0);
  const size_t qg0 = (size_t)(b * 4096 + qt * 128 + w * 32);
#pragma unroll
  for (int it = 0; it < 10; ++it) {
    int idx = it * 64 + lane;
    int row = idx / 20, cc = idx % 20;
    bf16x8 vch = *(const bf16x8*)(tr + row * 168 + cc * 8);
    *(bf16x8*)(AO + (qg0 + row) * 1280 + h * 160 + cc * 8) = vch;
  }
}

// ---------------------------------------------------------------------------
extern "C" void kernel_launch(void* const* d_in, const int* in_sizes, int n_in,
                              void* d_out, int out_size, void* d_ws, size_t ws_size,
                              hipStream_t stream) {
  const float* hs  = (const float*)d_in[0];
  const float* w_q = (const float*)d_in[1];
  const float* w_k = (const float*)d_in[2];
  const float* w_v = (const float*)d_in[3];
  const float* lka = (const float*)d_in[4];
  const float* lkb = (const float*)d_in[5];
  const float* lva = (const float*)d_in[6];
  const float* lvb = (const float*)d_in[7];
  const float* w_o = (const float*)d_in[8];
  const float* b_o = (const float*)d_in[9];
  float* out = (float*)d_out;
  char* ws = (char*)d_ws;

  const size_t KA  = 0;                      // 1280*4 f32
  const size_t VA  = 20480;
  const size_t WTQ = 40960;                  // 1280*1280 bf16 each
  const size_t WTK = WTQ + 3276800;
  const size_t WTV = WTK + 3276800;
  const size_t WTO = WTV + 3276800;
  const size_t HSB = WTO + 3276800;          // 8192*1280 bf16 each below
  const size_t QB  = HSB + 20971520;
  const size_t KB  = QB + 20971520;
  const size_t VB  = KB + 20971520;
  const size_t VTB = VB + 20971520;
  const size_t AOB = VTB + 20971520;
  const size_t END = AOB + 20971520;
  if (ws_size < END) return;  // leaves poison -> clear validation failure

  float* tk = (float*)(ws + KA);
  float* tv = (float*)(ws + VA);
  u16* wtq = (u16*)(ws + WTQ);
  u16* wtk = (u16*)(ws + WTK);
  u16* wtv = (u16*)(ws + WTV);
  u16* wto = (u16*)(ws + WTO);
  u16* hsb = (u16*)(ws + HSB);
  u16* qb  = (u16*)(ws + QB);
  u16* kb  = (u16*)(ws + KB);
  u16* vb  = (u16*)(ws + VB);
  u16* vtb = (u16*)(ws + VTB);
  u16* aob = (u16*)(ws + AOB);

  lora_tmp_k<<<dim3(1280, 2), 256, 0, stream>>>(w_k, w_v, lka, lva, tk, tv);
  wt_prep_k<<<dim3(40, 40), dim3(32, 8), 0, stream>>>(w_q, nullptr, nullptr, wtq);
  wt_prep_k<<<dim3(40, 40), dim3(32, 8), 0, stream>>>(w_k, tk, lkb, wtk);
  wt_prep_k<<<dim3(40, 40), dim3(32, 8), 0, stream>>>(w_v, tv, lvb, wtv);
  wt_prep_k<<<dim3(40, 40), dim3(32, 8), 0, stream>>>(w_o, nullptr, nullptr, wto);
  cvt_bf16_k<<<2048, 256, 0, stream>>>(hs, hsb, 2621440);

  const float qscale = 0.07905694150420949f;  // 1/sqrt(160)
  gemm128_k<false><<<dim3(64, 10), 256, 0, stream>>>(hsb, wtq, qb, nullptr, qscale);
  gemm128_k<false><<<dim3(64, 10), 256, 0, stream>>>(hsb, wtk, kb, nullptr, 1.0f);
  gemm128_k<false><<<dim3(64, 10), 256, 0, stream>>>(hsb, wtv, vb, nullptr, 1.0f);
  vtrans_k<<<dim3(128, 40, 2), dim3(32, 8), 0, stream>>>(vb, vtb);
  attn_k<<<dim3(16, 32), 256, 0, stream>>>(qb, kb, vtb, aob);
  gemm128_k<true><<<dim3(64, 10), 256, 0, stream>>>(aob, wto, (void*)out, b_o, 1.0f);
}